// Round 4
// baseline (189.109 us; speedup 1.0000x reference)
//
#include <hip/hip_runtime.h>

#define N_NODES 50000
#define N_EDGES 800000
#define DFEAT 96

// range partitioning: 7 ranges x 8192 nodes; 40 edge chunks of 20000
#define RBITS  13
#define RSIZE  8192
#define NRANGE 7
#define NCHUNK 40
#define CHUNK_E (N_EDGES / NCHUNK)   // 20000

// ---- pass 1: per-(range,chunk) LDS histograms of src and dst ----
__global__ __launch_bounds__(256) void deg_hist_kernel(
    const int* __restrict__ src, const int* __restrict__ dst,
    int* __restrict__ pout, int* __restrict__ pin) {
    __shared__ int hout[RSIZE];
    __shared__ int hin[RSIZE];
    int tid = threadIdx.x;
    int r = blockIdx.x % NRANGE;
    int c = blockIdx.x / NRANGE;
    for (int i = tid; i < RSIZE; i += 256) { hout[i] = 0; hin[i] = 0; }
    __syncthreads();
    int lo = r << RBITS;
    const int4* s4 = (const int4*)(src + c * CHUNK_E);
    const int4* d4 = (const int4*)(dst + c * CHUNK_E);
    for (int i = tid; i < CHUNK_E / 4; i += 256) {
        int4 s = s4[i];
        int4 d = d4[i];
        unsigned a;
        a = (unsigned)(s.x - lo); if (a < RSIZE) atomicAdd(&hout[a], 1);
        a = (unsigned)(s.y - lo); if (a < RSIZE) atomicAdd(&hout[a], 1);
        a = (unsigned)(s.z - lo); if (a < RSIZE) atomicAdd(&hout[a], 1);
        a = (unsigned)(s.w - lo); if (a < RSIZE) atomicAdd(&hout[a], 1);
        a = (unsigned)(d.x - lo); if (a < RSIZE) atomicAdd(&hin[a], 1);
        a = (unsigned)(d.y - lo); if (a < RSIZE) atomicAdd(&hin[a], 1);
        a = (unsigned)(d.z - lo); if (a < RSIZE) atomicAdd(&hin[a], 1);
        a = (unsigned)(d.w - lo); if (a < RSIZE) atomicAdd(&hin[a], 1);
    }
    __syncthreads();
    size_t base = (size_t)(r * NCHUNK + c) << RBITS;
    for (int i = tid; i < RSIZE; i += 256) {
        pout[base + i] = hout[i];
        pin[base + i]  = hin[i];
    }
}

// ---- pass 2: reduce to degrees, rewrite pin as per-chunk prefix, emit block sums ----
__global__ __launch_bounds__(256) void deg_reduce_kernel(
    const int* __restrict__ pout, int* __restrict__ pin,
    int* __restrict__ deg_out, int* __restrict__ deg_in,
    int* __restrict__ bsum) {
    __shared__ int ws[4];
    int tid = threadIdx.x;
    int n = blockIdx.x * 256 + tid;
    int so = 0, si = 0;
    if (n < N_NODES) {
        int r = n >> RBITS, bb = n & (RSIZE - 1);
        size_t stride = (size_t)1 << RBITS;
        const int* po = pout + (((size_t)r * NCHUNK) << RBITS) + bb;
        int*       pi = pin  + (((size_t)r * NCHUNK) << RBITS) + bb;
        #pragma unroll 8
        for (int c = 0; c < NCHUNK; ++c) {
            so += po[c * stride];
            int t = pi[c * stride];
            pi[c * stride] = si;   // exclusive prefix over chunks
            si += t;
        }
        deg_out[n] = so;
        deg_in[n]  = si;
    }
    // block-sum of si for the scan (this block == one scan block of 256 nodes)
    int v = si;
    #pragma unroll
    for (int off = 32; off; off >>= 1) v += __shfl_down(v, off, 64);
    if ((tid & 63) == 0) ws[tid >> 6] = v;
    __syncthreads();
    if (tid == 0) bsum[blockIdx.x] = ws[0] + ws[1] + ws[2] + ws[3];
}

// ---- scan of block sums (single block) ----
__global__ __launch_bounds__(256) void scan_base_kernel(
    const int* __restrict__ bsum, int* __restrict__ bbase,
    int* __restrict__ offs, int nb) {
    __shared__ int wsum[4];
    int tid = threadIdx.x, lane = tid & 63, wave = tid >> 6;
    int v = (tid < nb) ? bsum[tid] : 0;
    int x = v;
    #pragma unroll
    for (int off = 1; off < 64; off <<= 1) {
        int t = __shfl_up(x, off, 64);
        if (lane >= off) x += t;
    }
    if (lane == 63) wsum[wave] = x;
    __syncthreads();
    int wb = 0;
    for (int w = 0; w < wave; ++w) wb += wsum[w];
    if (tid < nb) bbase[tid] = wb + x - v;
    if (tid == 0) offs[N_NODES] = wsum[0] + wsum[1] + wsum[2] + wsum[3];
}

__global__ __launch_bounds__(256) void scan_final_kernel(
    const int* __restrict__ deg, const int* __restrict__ bbase,
    int* __restrict__ offs) {
    __shared__ int wsum[4];
    int tid = threadIdx.x, lane = tid & 63, wave = tid >> 6;
    int i = blockIdx.x * 256 + tid;
    int v = (i < N_NODES) ? deg[i] : 0;
    int x = v;
    #pragma unroll
    for (int off = 1; off < 64; off <<= 1) {
        int t = __shfl_up(x, off, 64);
        if (lane >= off) x += t;
    }
    if (lane == 63) wsum[wave] = x;
    __syncthreads();
    int wb = 0;
    for (int w = 0; w < wave; ++w) wb += wsum[w];
    if (i < N_NODES) offs[i] = bbase[blockIdx.x] + wb + x - v;
}

// ---- pass 3: CSR fill via LDS cursors (no global atomics) ----
__global__ __launch_bounds__(256) void fill_kernel(
    const int* __restrict__ src, const int* __restrict__ dst,
    const int* __restrict__ offs, const int* __restrict__ pin,
    int* __restrict__ csr_src) {
    __shared__ int cur[RSIZE];
    int tid = threadIdx.x;
    int r = blockIdx.x % NRANGE;
    int c = blockIdx.x / NRANGE;
    int lo = r << RBITS;
    const int* pf = pin + ((size_t)(r * NCHUNK + c) << RBITS);
    for (int i = tid; i < RSIZE; i += 256) {
        int gi = lo + i;
        int o = (gi < N_NODES) ? offs[gi] : 0;
        cur[i] = o + pf[i];
    }
    __syncthreads();
    const int4* s4 = (const int4*)(src + c * CHUNK_E);
    const int4* d4 = (const int4*)(dst + c * CHUNK_E);
    for (int i = tid; i < CHUNK_E / 4; i += 256) {
        int4 s = s4[i];
        int4 d = d4[i];
        unsigned a;
        a = (unsigned)(d.x - lo); if (a < RSIZE) csr_src[atomicAdd(&cur[a], 1)] = s.x;
        a = (unsigned)(d.y - lo); if (a < RSIZE) csr_src[atomicAdd(&cur[a], 1)] = s.y;
        a = (unsigned)(d.z - lo); if (a < RSIZE) csr_src[atomicAdd(&cur[a], 1)] = s.z;
        a = (unsigned)(d.w - lo); if (a < RSIZE) csr_src[atomicAdd(&cur[a], 1)] = s.w;
    }
}

// ---- RNE fp32->bf16 pair pack ----
__device__ __forceinline__ unsigned bpack(float a, float b) {
    unsigned ua = __float_as_uint(a);
    unsigned ub = __float_as_uint(b);
    ua = (ua + 0x7FFFu + ((ua >> 16) & 1u)) >> 16;
    ub = (ub + 0x7FFFu + ((ub >> 16) & 1u)) >> 16;
    return ua | (ub << 16);
}

// ---- GEMM: h = bf16( (x @ W) * inv_sqrt(deg_out[row]) ) ----
// 128 rows/block, 256 threads, thread = 4 rows x 12 cols.
// One b128 x-read feeds 4 rows -> LDS cycles/row drop ~1.75x vs 2-row variant.
#define GR 128
__global__ __launch_bounds__(256) void gemm_kernel(
    const float* __restrict__ x, const float* __restrict__ W,
    const int* __restrict__ deg_out, unsigned* __restrict__ h, int nrows) {
    __shared__ float ws[96 * 96];    // 36 KB
    __shared__ float xT[96 * GR];    // 48 KB, xT[col][row] -> 84 KB total, 1 block/CU
    int tid = threadIdx.x;

    const float4* Wv = (const float4*)W;
    float4* wv = (float4*)ws;
    #pragma unroll
    for (int i = 0; i < 9; ++i) wv[tid + 256 * i] = Wv[tid + 256 * i];

    int r0 = blockIdx.x * GR;
    int nvalid = nrows - r0; if (nvalid > GR) nvalid = GR;
    const float4* xv = (const float4*)x;
    for (int i = tid; i < 24 * GR; i += 256) {
        int row = i & (GR - 1);
        int c4 = i >> 7;
        if (row < nvalid) {
            float4 v = xv[(size_t)(r0 + row) * 24 + c4];
            xT[(c4 * 4 + 0) * GR + row] = v.x;
            xT[(c4 * 4 + 1) * GR + row] = v.y;
            xT[(c4 * 4 + 2) * GR + row] = v.z;
            xT[(c4 * 4 + 3) * GR + row] = v.w;
        }
    }
    __syncthreads();

    int rg = tid >> 3;            // 0..31 -> rows rg*4 .. rg*4+3
    int cg = tid & 7;             // cols 12*cg .. 12*cg+11
    float4 a0[4], a1[4], a2[4];
    #pragma unroll
    for (int r = 0; r < 4; ++r) { a0[r] = {0,0,0,0}; a1[r] = {0,0,0,0}; a2[r] = {0,0,0,0}; }

    #pragma unroll 8
    for (int k = 0; k < 96; ++k) {
        float4 xs = *(const float4*)&xT[k * GR + rg * 4];
        float4 w0 = *(const float4*)&ws[k * 96 + 12 * cg];
        float4 w1 = *(const float4*)&ws[k * 96 + 12 * cg + 4];
        float4 w2 = *(const float4*)&ws[k * 96 + 12 * cg + 8];
        float xr[4] = {xs.x, xs.y, xs.z, xs.w};
        #pragma unroll
        for (int r = 0; r < 4; ++r) {
            a0[r].x += xr[r] * w0.x; a0[r].y += xr[r] * w0.y; a0[r].z += xr[r] * w0.z; a0[r].w += xr[r] * w0.w;
            a1[r].x += xr[r] * w1.x; a1[r].y += xr[r] * w1.y; a1[r].z += xr[r] * w1.z; a1[r].w += xr[r] * w1.w;
            a2[r].x += xr[r] * w2.x; a2[r].y += xr[r] * w2.y; a2[r].z += xr[r] * w2.z; a2[r].w += xr[r] * w2.w;
        }
    }

    #pragma unroll
    for (int r = 0; r < 4; ++r) {
        int row = r0 + rg * 4 + r;
        if (row < nrows) {
            int d = deg_out[row];
            float s = (d > 0) ? rsqrtf((float)d) : 0.f;
            unsigned* hp = h + (size_t)row * 48 + 6 * cg;
            uint2 p0, p1, p2;
            p0.x = bpack(a0[r].x * s, a0[r].y * s);
            p0.y = bpack(a0[r].z * s, a0[r].w * s);
            p1.x = bpack(a1[r].x * s, a1[r].y * s);
            p1.y = bpack(a1[r].z * s, a1[r].w * s);
            p2.x = bpack(a2[r].x * s, a2[r].y * s);
            p2.y = bpack(a2[r].z * s, a2[r].w * s);
            *(uint2*)(hp)     = p0;
            *(uint2*)(hp + 2) = p1;
            *(uint2*)(hp + 4) = p2;
        }
    }
}

// ---- aggregate: out[n] = inv_sqrt_in[n] * sum h[src_e] + b ----
// 8 lanes/node: two 4-lane half-groups process even/odd edges, shfl_xor(4) combine.
__device__ __forceinline__ void upadd(float* a, uint4 q) {
    a[0] += __uint_as_float(q.x << 16);
    a[1] += __uint_as_float(q.x & 0xffff0000u);
    a[2] += __uint_as_float(q.y << 16);
    a[3] += __uint_as_float(q.y & 0xffff0000u);
    a[4] += __uint_as_float(q.z << 16);
    a[5] += __uint_as_float(q.z & 0xffff0000u);
    a[6] += __uint_as_float(q.w << 16);
    a[7] += __uint_as_float(q.w & 0xffff0000u);
}

__global__ __launch_bounds__(256) void agg_kernel(
    const unsigned* __restrict__ h, const int* __restrict__ csr_src,
    const int* __restrict__ offs, const float* __restrict__ b,
    float* __restrict__ out, int nnodes) {
    int tid = threadIdx.x;
    int n = blockIdx.x * 32 + (tid >> 3);
    if (n >= nnodes) return;
    int j = tid & 3;                    // uint4 slots j, j+4, j+8 of each row
    int half = (tid >> 2) & 1;          // even/odd edge split
    int start = offs[n], end = offs[n + 1];
    float acc[24];
    #pragma unroll
    for (int i = 0; i < 24; ++i) acc[i] = 0.f;
    const uint4* hb = (const uint4*)h;  // row = 12 uint4
    int e = start + half;
    for (; e + 2 < end; e += 4) {       // edges e and e+2 (this half's stride-2 list)
        size_t b0 = (size_t)csr_src[e] * 12 + j;
        size_t b1 = (size_t)csr_src[e + 2] * 12 + j;
        uint4 q0 = hb[b0], q1 = hb[b0 + 4], q2 = hb[b0 + 8];
        uint4 p0 = hb[b1], p1 = hb[b1 + 4], p2 = hb[b1 + 8];
        upadd(acc + 0, q0); upadd(acc + 8, q1); upadd(acc + 16, q2);
        upadd(acc + 0, p0); upadd(acc + 8, p1); upadd(acc + 16, p2);
    }
    if (e < end) {
        size_t b0 = (size_t)csr_src[e] * 12 + j;
        uint4 q0 = hb[b0], q1 = hb[b0 + 4], q2 = hb[b0 + 8];
        upadd(acc + 0, q0); upadd(acc + 8, q1); upadd(acc + 16, q2);
    }
    // combine the two halves (partner lane = tid ^ 4, same j)
    #pragma unroll
    for (int i = 0; i < 24; ++i) acc[i] += __shfl_xor(acc[i], 4, 64);
    if (half) return;
    float inv = (end > start) ? rsqrtf((float)(end - start)) : 0.f;
    #pragma unroll
    for (int g = 0; g < 3; ++g) {
        int q = j + 4 * g;              // cols 8q .. 8q+7
        float4 bb0 = *(const float4*)(b + 8 * q);
        float4 bb1 = *(const float4*)(b + 8 * q + 4);
        float4 r0, r1;
        r0.x = acc[g * 8 + 0] * inv + bb0.x;
        r0.y = acc[g * 8 + 1] * inv + bb0.y;
        r0.z = acc[g * 8 + 2] * inv + bb0.z;
        r0.w = acc[g * 8 + 3] * inv + bb0.w;
        r1.x = acc[g * 8 + 4] * inv + bb1.x;
        r1.y = acc[g * 8 + 5] * inv + bb1.y;
        r1.z = acc[g * 8 + 6] * inv + bb1.z;
        r1.w = acc[g * 8 + 7] * inv + bb1.w;
        float4* o = (float4*)(out + (size_t)n * DFEAT + 8 * q);
        o[0] = r0; o[1] = r1;
    }
}

extern "C" void kernel_launch(void* const* d_in, const int* in_sizes, int n_in,
                              void* d_out, int out_size, void* d_ws, size_t ws_size,
                              hipStream_t stream) {
    const float* x  = (const float*)d_in[0];
    const float* W  = (const float*)d_in[1];
    const float* b  = (const float*)d_in[2];
    const int*   src = (const int*)d_in[3];
    const int*   dst = (const int*)d_in[4];
    float* out = (float*)d_out;

    // workspace layout
    int* deg_out = (int*)d_ws;                   // 50000
    int* deg_in  = deg_out + N_NODES;            // 50000
    int* offs    = deg_in + N_NODES;             // 50001
    int* csr_src = offs + N_NODES + 1;           // 800000
    int* bsum    = csr_src + N_EDGES;            // 196
    int* bbase   = bsum + 196;                   // 196
    size_t tbl_off = (((size_t)(2 * N_NODES + N_NODES + 1 + N_EDGES + 392)) * 4 + 255) & ~(size_t)255;
    int* pout = (int*)((char*)d_ws + tbl_off);               // 7*40*8192 ints
    int* pin  = pout + ((size_t)NRANGE * NCHUNK << RBITS);
    // h (bf16, 9.6 MB) aliases pout and spills ~0.4 MB into pin:
    // pin must be fully consumed (by fill) before gemm writes h. Keep fill -> gemm order.
    unsigned* h = (unsigned*)pout;

    deg_hist_kernel<<<NRANGE * NCHUNK, 256, 0, stream>>>(src, dst, pout, pin);

    int nb = (N_NODES + 255) / 256;  // 196
    deg_reduce_kernel<<<nb, 256, 0, stream>>>(pout, pin, deg_out, deg_in, bsum);
    scan_base_kernel<<<1, 256, 0, stream>>>(bsum, bbase, offs, nb);
    scan_final_kernel<<<nb, 256, 0, stream>>>(deg_in, bbase, offs);

    fill_kernel<<<NRANGE * NCHUNK, 256, 0, stream>>>(src, dst, offs, pin, csr_src);

    gemm_kernel<<<(N_NODES + GR - 1) / GR, 256, 0, stream>>>(x, W, deg_out, h, N_NODES);

    agg_kernel<<<(N_NODES + 31) / 32, 256, 0, stream>>>(h, csr_src, offs, b, out, N_NODES);
}

// Round 5
// 179.142 us; speedup vs baseline: 1.0556x; 1.0556x over previous
//
#include <hip/hip_runtime.h>

#define N_NODES 50000
#define N_EDGES 800000
#define DFEAT 96

// range partitioning: 4 ranges x 16384 nodes; 40 edge chunks of 20000
#define RBITS  14
#define RSIZE  16384
#define NRANGE 4
#define NCHUNK 40
#define CHUNK_E (N_EDGES / NCHUNK)   // 20000
#define FILL_BLOCKS (NRANGE * NCHUNK)  // 160

// ---- pass 1: per-(range,chunk) LDS histograms of src and dst ----
// 128 KB static LDS (gfx950 allows up to 160 KB; 84 KB verified compiling in r3/r4)
__global__ __launch_bounds__(256) void deg_hist_kernel(
    const int* __restrict__ src, const int* __restrict__ dst,
    int* __restrict__ pout, int* __restrict__ pin) {
    __shared__ int hout[RSIZE];
    __shared__ int hin[RSIZE];
    int tid = threadIdx.x;
    int r = blockIdx.x % NRANGE;
    int c = blockIdx.x / NRANGE;
    for (int i = tid; i < RSIZE; i += 256) { hout[i] = 0; hin[i] = 0; }
    __syncthreads();
    int lo = r << RBITS;
    const int4* s4 = (const int4*)(src + c * CHUNK_E);
    const int4* d4 = (const int4*)(dst + c * CHUNK_E);
    for (int i = tid; i < CHUNK_E / 4; i += 256) {
        int4 s = s4[i];
        int4 d = d4[i];
        unsigned a;
        a = (unsigned)(s.x - lo); if (a < RSIZE) atomicAdd(&hout[a], 1);
        a = (unsigned)(s.y - lo); if (a < RSIZE) atomicAdd(&hout[a], 1);
        a = (unsigned)(s.z - lo); if (a < RSIZE) atomicAdd(&hout[a], 1);
        a = (unsigned)(s.w - lo); if (a < RSIZE) atomicAdd(&hout[a], 1);
        a = (unsigned)(d.x - lo); if (a < RSIZE) atomicAdd(&hin[a], 1);
        a = (unsigned)(d.y - lo); if (a < RSIZE) atomicAdd(&hin[a], 1);
        a = (unsigned)(d.z - lo); if (a < RSIZE) atomicAdd(&hin[a], 1);
        a = (unsigned)(d.w - lo); if (a < RSIZE) atomicAdd(&hin[a], 1);
    }
    __syncthreads();
    size_t base = (size_t)(r * NCHUNK + c) << RBITS;
    for (int i = tid; i < RSIZE; i += 256) {
        pout[base + i] = hout[i];
        pin[base + i]  = hin[i];
    }
}

// ---- pass 2: reduce to degrees, rewrite pin as per-chunk prefix, emit block sums ----
__global__ __launch_bounds__(256) void deg_reduce_kernel(
    const int* __restrict__ pout, int* __restrict__ pin,
    int* __restrict__ deg_out, int* __restrict__ deg_in,
    int* __restrict__ bsum) {
    __shared__ int ws[4];
    int tid = threadIdx.x;
    int n = blockIdx.x * 256 + tid;
    int so = 0, si = 0;
    if (n < N_NODES) {
        int r = n >> RBITS, bb = n & (RSIZE - 1);
        size_t stride = (size_t)1 << RBITS;
        const int* po = pout + (((size_t)r * NCHUNK) << RBITS) + bb;
        int*       pi = pin  + (((size_t)r * NCHUNK) << RBITS) + bb;
        #pragma unroll 8
        for (int c = 0; c < NCHUNK; ++c) {
            so += po[c * stride];
            int t = pi[c * stride];
            pi[c * stride] = si;   // exclusive prefix over chunks
            si += t;
        }
        deg_out[n] = so;
        deg_in[n]  = si;
    }
    int v = si;
    #pragma unroll
    for (int off = 32; off; off >>= 1) v += __shfl_down(v, off, 64);
    if ((tid & 63) == 0) ws[tid >> 6] = v;
    __syncthreads();
    if (tid == 0) bsum[blockIdx.x] = ws[0] + ws[1] + ws[2] + ws[3];
}

// ---- pass 3: scan. Each block recomputes its base from bsum (no scan_base kernel) ----
__global__ __launch_bounds__(256) void scan_final_kernel(
    const int* __restrict__ deg, const int* __restrict__ bsum,
    int* __restrict__ offs, int nb) {
    __shared__ int wsum[4];
    __shared__ int sbase;
    int tid = threadIdx.x, lane = tid & 63, wave = tid >> 6;
    int i = blockIdx.x * 256 + tid;
    int v = (i < N_NODES) ? deg[i] : 0;
    int x = v;
    #pragma unroll
    for (int off = 1; off < 64; off <<= 1) {
        int t = __shfl_up(x, off, 64);
        if (lane >= off) x += t;
    }
    if (lane == 63) wsum[wave] = x;
    if (wave == 0) {                         // block base = sum bsum[0..blockIdx)
        int s = 0;
        for (int j = lane; j < blockIdx.x; j += 64) s += bsum[j];
        #pragma unroll
        for (int off = 32; off; off >>= 1) s += __shfl_down(s, off, 64);
        if (lane == 0) sbase = s;
    }
    if (blockIdx.x == gridDim.x - 1 && wave == 1) {   // grand total
        int s = 0;
        for (int j = lane; j < nb; j += 64) s += bsum[j];
        #pragma unroll
        for (int off = 32; off; off >>= 1) s += __shfl_down(s, off, 64);
        if (lane == 0) offs[N_NODES] = s;
    }
    __syncthreads();
    int wb = sbase;
    for (int w = 0; w < wave; ++w) wb += wsum[w];
    if (i < N_NODES) offs[i] = wb + x - v;
}

// ---- RNE fp32->bf16 pair pack ----
__device__ __forceinline__ unsigned bpack(float a, float b) {
    unsigned ua = __float_as_uint(a);
    unsigned ub = __float_as_uint(b);
    ua = (ua + 0x7FFFu + ((ua >> 16) & 1u)) >> 16;
    ub = (ub + 0x7FFFu + ((ub >> 16) & 1u)) >> 16;
    return ua | (ub << 16);
}

// ---- pass 4 (fused): blocks [0,160) CSR-fill via LDS cursors; blocks [160,942) GEMM ----
// fill reads pin/offs/src/dst -> csr_src; gemm reads x/W/deg_out -> h (aliases dead pout).
// Disjoint data; mixes atomic-heavy and VALU-heavy blocks on the same CUs.
#define GR 64
__global__ __launch_bounds__(256) void fillgemm_kernel(
    const int* __restrict__ src, const int* __restrict__ dst,
    const int* __restrict__ offs, const int* __restrict__ pin,
    int* __restrict__ csr_src,
    const float* __restrict__ x, const float* __restrict__ W,
    const int* __restrict__ deg_out, unsigned* __restrict__ h, int nrows) {
    __shared__ int smem[RSIZE];          // 64 KB; gemm path reuses as float ws[9216]
    int tid = threadIdx.x;

    if (blockIdx.x < FILL_BLOCKS) {
        // ---------------- fill path ----------------
        int* cur = smem;
        int r = blockIdx.x % NRANGE;
        int c = blockIdx.x / NRANGE;
        int lo = r << RBITS;
        const int* pf = pin + ((size_t)(r * NCHUNK + c) << RBITS);
        for (int i = tid; i < RSIZE; i += 256) {
            int gi = lo + i;
            int o = (gi < N_NODES) ? offs[gi] : 0;
            cur[i] = o + pf[i];
        }
        __syncthreads();
        const int4* s4 = (const int4*)(src + c * CHUNK_E);
        const int4* d4 = (const int4*)(dst + c * CHUNK_E);
        for (int i = tid; i < CHUNK_E / 4; i += 256) {
            int4 s = s4[i];
            int4 d = d4[i];
            unsigned a;
            a = (unsigned)(d.x - lo); if (a < RSIZE) csr_src[atomicAdd(&cur[a], 1)] = s.x;
            a = (unsigned)(d.y - lo); if (a < RSIZE) csr_src[atomicAdd(&cur[a], 1)] = s.y;
            a = (unsigned)(d.z - lo); if (a < RSIZE) csr_src[atomicAdd(&cur[a], 1)] = s.z;
            a = (unsigned)(d.w - lo); if (a < RSIZE) csr_src[atomicAdd(&cur[a], 1)] = s.w;
        }
        return;
    }

    // ---------------- gemm path: h = bf16((x @ W) * inv_sqrt(deg_out)) ----------------
    // W in LDS (36 KB, 8-unique-address broadcast reads); x streamed from global
    // (8x redundant across cg lanes, 24 KB tile is L1-resident). 2 rows x 12 cols/thread.
    float* ws = (float*)smem;
    const float4* Wv = (const float4*)W;
    float4* wv = (float4*)ws;
    for (int i = tid; i < 2304; i += 256) wv[i] = Wv[i];
    __syncthreads();

    int bid = blockIdx.x - FILL_BLOCKS;
    int r0 = bid * GR;
    int rg = tid >> 3;             // 0..31 -> rows rg*2, rg*2+1
    int cg = tid & 7;              // cols 12*cg .. 12*cg+11
    int row0 = r0 + rg * 2, row1 = row0 + 1;
    int row0c = row0 < nrows ? row0 : nrows - 1;
    int row1c = row1 < nrows ? row1 : nrows - 1;
    const float4* xv = (const float4*)x;
    size_t xb0 = (size_t)row0c * 24, xb1 = (size_t)row1c * 24;

    float4 a0[2], a1[2], a2[2];
    #pragma unroll
    for (int r = 0; r < 2; ++r) { a0[r] = {0,0,0,0}; a1[r] = {0,0,0,0}; a2[r] = {0,0,0,0}; }

    #pragma unroll 4
    for (int q = 0; q < 24; ++q) {
        float4 xa = xv[xb0 + q];
        float4 xb = xv[xb1 + q];
        float xr0[4] = {xa.x, xa.y, xa.z, xa.w};
        float xr1[4] = {xb.x, xb.y, xb.z, xb.w};
        #pragma unroll
        for (int kk = 0; kk < 4; ++kk) {
            int k = q * 4 + kk;
            float4 w0 = *(const float4*)&ws[k * 96 + 12 * cg];
            float4 w1 = *(const float4*)&ws[k * 96 + 12 * cg + 4];
            float4 w2 = *(const float4*)&ws[k * 96 + 12 * cg + 8];
            a0[0].x += xr0[kk] * w0.x; a0[0].y += xr0[kk] * w0.y; a0[0].z += xr0[kk] * w0.z; a0[0].w += xr0[kk] * w0.w;
            a1[0].x += xr0[kk] * w1.x; a1[0].y += xr0[kk] * w1.y; a1[0].z += xr0[kk] * w1.z; a1[0].w += xr0[kk] * w1.w;
            a2[0].x += xr0[kk] * w2.x; a2[0].y += xr0[kk] * w2.y; a2[0].z += xr0[kk] * w2.z; a2[0].w += xr0[kk] * w2.w;
            a0[1].x += xr1[kk] * w0.x; a0[1].y += xr1[kk] * w0.y; a0[1].z += xr1[kk] * w0.z; a0[1].w += xr1[kk] * w0.w;
            a1[1].x += xr1[kk] * w1.x; a1[1].y += xr1[kk] * w1.y; a1[1].z += xr1[kk] * w1.z; a1[1].w += xr1[kk] * w1.w;
            a2[1].x += xr1[kk] * w2.x; a2[1].y += xr1[kk] * w2.y; a2[1].z += xr1[kk] * w2.z; a2[1].w += xr1[kk] * w2.w;
        }
    }

    #pragma unroll
    for (int r = 0; r < 2; ++r) {
        int row = row0 + r;
        if (row < nrows) {
            int d = deg_out[row];
            float s = (d > 0) ? rsqrtf((float)d) : 0.f;
            unsigned* hp = h + (size_t)row * 48 + 6 * cg;
            uint2 p0, p1, p2;
            p0.x = bpack(a0[r].x * s, a0[r].y * s);
            p0.y = bpack(a0[r].z * s, a0[r].w * s);
            p1.x = bpack(a1[r].x * s, a1[r].y * s);
            p1.y = bpack(a1[r].z * s, a1[r].w * s);
            p2.x = bpack(a2[r].x * s, a2[r].y * s);
            p2.y = bpack(a2[r].z * s, a2[r].w * s);
            *(uint2*)(hp)     = p0;
            *(uint2*)(hp + 2) = p1;
            *(uint2*)(hp + 4) = p2;
        }
    }
}

// ---- aggregate: out[n] = inv_sqrt_in[n] * sum h[src_e] + b ----
// 8 lanes/node: two 4-lane half-groups over even/odd edges, shfl_xor(4) combine.
__device__ __forceinline__ void upadd(float* a, uint4 q) {
    a[0] += __uint_as_float(q.x << 16);
    a[1] += __uint_as_float(q.x & 0xffff0000u);
    a[2] += __uint_as_float(q.y << 16);
    a[3] += __uint_as_float(q.y & 0xffff0000u);
    a[4] += __uint_as_float(q.z << 16);
    a[5] += __uint_as_float(q.z & 0xffff0000u);
    a[6] += __uint_as_float(q.w << 16);
    a[7] += __uint_as_float(q.w & 0xffff0000u);
}

__global__ __launch_bounds__(256) void agg_kernel(
    const unsigned* __restrict__ h, const int* __restrict__ csr_src,
    const int* __restrict__ offs, const float* __restrict__ b,
    float* __restrict__ out, int nnodes) {
    int tid = threadIdx.x;
    int n = blockIdx.x * 32 + (tid >> 3);
    if (n >= nnodes) return;
    int j = tid & 3;                    // uint4 slots j, j+4, j+8 of each row
    int half = (tid >> 2) & 1;          // even/odd edge split
    int start = offs[n], end = offs[n + 1];
    float acc[24];
    #pragma unroll
    for (int i = 0; i < 24; ++i) acc[i] = 0.f;
    const uint4* hb = (const uint4*)h;  // row = 12 uint4
    int e = start + half;
    for (; e + 2 < end; e += 4) {
        size_t b0 = (size_t)csr_src[e] * 12 + j;
        size_t b1 = (size_t)csr_src[e + 2] * 12 + j;
        uint4 q0 = hb[b0], q1 = hb[b0 + 4], q2 = hb[b0 + 8];
        uint4 p0 = hb[b1], p1 = hb[b1 + 4], p2 = hb[b1 + 8];
        upadd(acc + 0, q0); upadd(acc + 8, q1); upadd(acc + 16, q2);
        upadd(acc + 0, p0); upadd(acc + 8, p1); upadd(acc + 16, p2);
    }
    if (e < end) {
        size_t b0 = (size_t)csr_src[e] * 12 + j;
        uint4 q0 = hb[b0], q1 = hb[b0 + 4], q2 = hb[b0 + 8];
        upadd(acc + 0, q0); upadd(acc + 8, q1); upadd(acc + 16, q2);
    }
    #pragma unroll
    for (int i = 0; i < 24; ++i) acc[i] += __shfl_xor(acc[i], 4, 64);
    if (half) return;
    float inv = (end > start) ? rsqrtf((float)(end - start)) : 0.f;
    #pragma unroll
    for (int g = 0; g < 3; ++g) {
        int q = j + 4 * g;              // cols 8q .. 8q+7
        float4 bb0 = *(const float4*)(b + 8 * q);
        float4 bb1 = *(const float4*)(b + 8 * q + 4);
        float4 r0, r1;
        r0.x = acc[g * 8 + 0] * inv + bb0.x;
        r0.y = acc[g * 8 + 1] * inv + bb0.y;
        r0.z = acc[g * 8 + 2] * inv + bb0.z;
        r0.w = acc[g * 8 + 3] * inv + bb0.w;
        r1.x = acc[g * 8 + 4] * inv + bb1.x;
        r1.y = acc[g * 8 + 5] * inv + bb1.y;
        r1.z = acc[g * 8 + 6] * inv + bb1.z;
        r1.w = acc[g * 8 + 7] * inv + bb1.w;
        float4* o = (float4*)(out + (size_t)n * DFEAT + 8 * q);
        o[0] = r0; o[1] = r1;
    }
}

extern "C" void kernel_launch(void* const* d_in, const int* in_sizes, int n_in,
                              void* d_out, int out_size, void* d_ws, size_t ws_size,
                              hipStream_t stream) {
    const float* x  = (const float*)d_in[0];
    const float* W  = (const float*)d_in[1];
    const float* b  = (const float*)d_in[2];
    const int*   src = (const int*)d_in[3];
    const int*   dst = (const int*)d_in[4];
    float* out = (float*)d_out;

    // workspace layout
    int* deg_out = (int*)d_ws;                   // 50000
    int* deg_in  = deg_out + N_NODES;            // 50000
    int* offs    = deg_in + N_NODES;             // 50001
    int* csr_src = offs + N_NODES + 1;           // 800000
    int* bsum    = csr_src + N_EDGES;            // 196
    size_t tbl_off = (((size_t)(2 * N_NODES + N_NODES + 1 + N_EDGES + 256)) * 4 + 255) & ~(size_t)255;
    int* pout = (int*)((char*)d_ws + tbl_off);               // 4*40*16384 = 2.62M ints (10.5 MB)
    int* pin  = pout + ((size_t)NRANGE * NCHUNK << RBITS);   // 10.5 MB
    // h (bf16, 9.6 MB) aliases pout entirely (pout dead after deg_reduce);
    // fill reads only pin/offs, so the fused fillgemm kernel is race-free.
    unsigned* h = (unsigned*)pout;

    deg_hist_kernel<<<NRANGE * NCHUNK, 256, 0, stream>>>(src, dst, pout, pin);

    int nb = (N_NODES + 255) / 256;  // 196
    deg_reduce_kernel<<<nb, 256, 0, stream>>>(pout, pin, deg_out, deg_in, bsum);
    scan_final_kernel<<<nb, 256, 0, stream>>>(deg_in, bsum, offs, nb);

    int gblocks = (N_NODES + GR - 1) / GR;  // 782
    fillgemm_kernel<<<FILL_BLOCKS + gblocks, 256, 0, stream>>>(
        src, dst, offs, pin, csr_src, x, W, deg_out, h, N_NODES);

    agg_kernel<<<(N_NODES + 31) / 32, 256, 0, stream>>>(h, csr_src, offs, b, out, N_NODES);
}

// Round 6
// 173.427 us; speedup vs baseline: 1.0904x; 1.0330x over previous
//
#include <hip/hip_runtime.h>

#define N_NODES 50000
#define N_EDGES 800000
#define DFEAT 96

// range partitioning: 4 ranges x 16384 nodes; 40 edge chunks of 20000
#define RBITS  14
#define RSIZE  16384
#define NRANGE 4
#define NCHUNK 40
#define CHUNK_E (N_EDGES / NCHUNK)     // 20000
#define FILL_BLOCKS (NRANGE * NCHUNK)  // 160

typedef short bf16x8 __attribute__((ext_vector_type(8)));
typedef float f32x4  __attribute__((ext_vector_type(4)));

// ---- RNE fp32->bf16 packing ----
__device__ __forceinline__ unsigned bpack(float a, float b) {
    unsigned ua = __float_as_uint(a);
    unsigned ub = __float_as_uint(b);
    ua = (ua + 0x7FFFu + ((ua >> 16) & 1u)) >> 16;
    ub = (ub + 0x7FFFu + ((ub >> 16) & 1u)) >> 16;
    return ua | (ub << 16);
}
__device__ __forceinline__ unsigned short b1(float a) {
    unsigned u = __float_as_uint(a);
    u = (u + 0x7FFFu + ((u >> 16) & 1u)) >> 16;
    return (unsigned short)u;
}

// ---- pass 1: per-(range,chunk) LDS histograms of src and dst ----
__global__ __launch_bounds__(256) void deg_hist_kernel(
    const int* __restrict__ src, const int* __restrict__ dst,
    int* __restrict__ pout, int* __restrict__ pin) {
    __shared__ int hout[RSIZE];
    __shared__ int hin[RSIZE];
    int tid = threadIdx.x;
    int r = blockIdx.x % NRANGE;
    int c = blockIdx.x / NRANGE;
    for (int i = tid; i < RSIZE; i += 256) { hout[i] = 0; hin[i] = 0; }
    __syncthreads();
    int lo = r << RBITS;
    const int4* s4 = (const int4*)(src + c * CHUNK_E);
    const int4* d4 = (const int4*)(dst + c * CHUNK_E);
    for (int i = tid; i < CHUNK_E / 4; i += 256) {
        int4 s = s4[i];
        int4 d = d4[i];
        unsigned a;
        a = (unsigned)(s.x - lo); if (a < RSIZE) atomicAdd(&hout[a], 1);
        a = (unsigned)(s.y - lo); if (a < RSIZE) atomicAdd(&hout[a], 1);
        a = (unsigned)(s.z - lo); if (a < RSIZE) atomicAdd(&hout[a], 1);
        a = (unsigned)(s.w - lo); if (a < RSIZE) atomicAdd(&hout[a], 1);
        a = (unsigned)(d.x - lo); if (a < RSIZE) atomicAdd(&hin[a], 1);
        a = (unsigned)(d.y - lo); if (a < RSIZE) atomicAdd(&hin[a], 1);
        a = (unsigned)(d.z - lo); if (a < RSIZE) atomicAdd(&hin[a], 1);
        a = (unsigned)(d.w - lo); if (a < RSIZE) atomicAdd(&hin[a], 1);
    }
    __syncthreads();
    size_t base = (size_t)(r * NCHUNK + c) << RBITS;
    for (int i = tid; i < RSIZE; i += 256) {
        pout[base + i] = hout[i];
        pin[base + i]  = hin[i];
    }
}

// ---- pass 2: reduce to degrees, rewrite pin as per-chunk prefix, emit block sums ----
__global__ __launch_bounds__(256) void deg_reduce_kernel(
    const int* __restrict__ pout, int* __restrict__ pin,
    int* __restrict__ deg_out, int* __restrict__ deg_in,
    int* __restrict__ bsum) {
    __shared__ int ws[4];
    int tid = threadIdx.x;
    int n = blockIdx.x * 256 + tid;
    int so = 0, si = 0;
    if (n < N_NODES) {
        int r = n >> RBITS, bb = n & (RSIZE - 1);
        size_t stride = (size_t)1 << RBITS;
        const int* po = pout + (((size_t)r * NCHUNK) << RBITS) + bb;
        int*       pi = pin  + (((size_t)r * NCHUNK) << RBITS) + bb;
        #pragma unroll 8
        for (int c = 0; c < NCHUNK; ++c) {
            so += po[c * stride];
            int t = pi[c * stride];
            pi[c * stride] = si;   // exclusive prefix over chunks
            si += t;
        }
        deg_out[n] = so;
        deg_in[n]  = si;
    }
    int v = si;
    #pragma unroll
    for (int off = 32; off; off >>= 1) v += __shfl_down(v, off, 64);
    if ((tid & 63) == 0) ws[tid >> 6] = v;
    __syncthreads();
    if (tid == 0) bsum[blockIdx.x] = ws[0] + ws[1] + ws[2] + ws[3];
}

// ---- pass 3: scan; each block recomputes its base from bsum ----
__global__ __launch_bounds__(256) void scan_final_kernel(
    const int* __restrict__ deg, const int* __restrict__ bsum,
    int* __restrict__ offs, int nb) {
    __shared__ int wsum[4];
    __shared__ int sbase;
    int tid = threadIdx.x, lane = tid & 63, wave = tid >> 6;
    int i = blockIdx.x * 256 + tid;
    int v = (i < N_NODES) ? deg[i] : 0;
    int x = v;
    #pragma unroll
    for (int off = 1; off < 64; off <<= 1) {
        int t = __shfl_up(x, off, 64);
        if (lane >= off) x += t;
    }
    if (lane == 63) wsum[wave] = x;
    if (wave == 0) {
        int s = 0;
        for (int j = lane; j < blockIdx.x; j += 64) s += bsum[j];
        #pragma unroll
        for (int off = 32; off; off >>= 1) s += __shfl_down(s, off, 64);
        if (lane == 0) sbase = s;
    }
    if (blockIdx.x == gridDim.x - 1 && wave == 1) {
        int s = 0;
        for (int j = lane; j < nb; j += 64) s += bsum[j];
        #pragma unroll
        for (int off = 32; off; off >>= 1) s += __shfl_down(s, off, 64);
        if (lane == 0) offs[N_NODES] = s;
    }
    __syncthreads();
    int wb = sbase;
    for (int w = 0; w < wave; ++w) wb += wsum[w];
    if (i < N_NODES) offs[i] = wb + x - v;
}

// ---- pass 4: CSR fill via LDS cursors (no global atomics) ----
__global__ __launch_bounds__(256) void fill_kernel(
    const int* __restrict__ src, const int* __restrict__ dst,
    const int* __restrict__ offs, const int* __restrict__ pin,
    int* __restrict__ csr_src) {
    __shared__ int cur[RSIZE];
    int tid = threadIdx.x;
    int r = blockIdx.x % NRANGE;
    int c = blockIdx.x / NRANGE;
    int lo = r << RBITS;
    const int* pf = pin + ((size_t)(r * NCHUNK + c) << RBITS);
    for (int i = tid; i < RSIZE; i += 256) {
        int gi = lo + i;
        int o = (gi < N_NODES) ? offs[gi] : 0;
        cur[i] = o + pf[i];
    }
    __syncthreads();
    const int4* s4 = (const int4*)(src + c * CHUNK_E);
    const int4* d4 = (const int4*)(dst + c * CHUNK_E);
    for (int i = tid; i < CHUNK_E / 4; i += 256) {
        int4 s = s4[i];
        int4 d = d4[i];
        unsigned a;
        a = (unsigned)(d.x - lo); if (a < RSIZE) csr_src[atomicAdd(&cur[a], 1)] = s.x;
        a = (unsigned)(d.y - lo); if (a < RSIZE) csr_src[atomicAdd(&cur[a], 1)] = s.y;
        a = (unsigned)(d.z - lo); if (a < RSIZE) csr_src[atomicAdd(&cur[a], 1)] = s.z;
        a = (unsigned)(d.w - lo); if (a < RSIZE) csr_src[atomicAdd(&cur[a], 1)] = s.w;
    }
}

// ---- pass 5: MFMA GEMM  h = bf16( (x @ W) * inv_sqrt(deg_out[row]) ) ----
// 64 rows/block, 4 waves; wave w owns rows [w*16, w*16+16).
// W^T (bf16, [n][k], ld=104 -> 2-way-free b128 frag reads) and the bf16 x-tile
// ([m][k], ld=104) staged in LDS (53 KB -> 3 blocks/CU).
#define GEMM_ROWS 64
#define TLD 104
__global__ __launch_bounds__(256) void gemm_kernel(
    const float* __restrict__ x, const float* __restrict__ W,
    const int* __restrict__ deg_out, unsigned short* __restrict__ h, int nrows) {
    __shared__ unsigned short WT[96 * TLD];         // 19.5 KB
    __shared__ unsigned short xA[GEMM_ROWS * TLD];  // 13 KB
    int tid = threadIdx.x;
    int r0 = blockIdx.x * GEMM_ROWS;

    // stage WT[n][k]: i = k2*96 + n -> coalesced W reads (2 rows of W per pair)
    for (int i = tid; i < 48 * 96; i += 256) {
        int k2 = i / 96, n = i - k2 * 96;
        float w0 = W[(size_t)(2 * k2) * 96 + n];
        float w1 = W[(size_t)(2 * k2 + 1) * 96 + n];
        *(unsigned*)&WT[n * TLD + 2 * k2] = bpack(w0, w1);
    }
    // stage xA[m][k]: i = m*48 + k2 -> coalesced float2 reads along k
    for (int i = tid; i < GEMM_ROWS * 48; i += 256) {
        int m = i / 48, k2 = i - m * 48;
        int row = r0 + m; if (row >= nrows) row = nrows - 1;
        float2 v = *(const float2*)&x[(size_t)row * 96 + 2 * k2];
        *(unsigned*)&xA[m * TLD + 2 * k2] = bpack(v.x, v.y);
    }
    __syncthreads();

    int lane = tid & 63, wave = tid >> 6;
    int m16 = lane & 15;          // A row / B col / C col
    int g = lane >> 4;            // k-group 0..3 (k = g*8 + j); C rows g*4..g*4+3
    int rbase = wave * 16;

    bf16x8 afrag[3];
    #pragma unroll
    for (int ks = 0; ks < 3; ++ks)
        afrag[ks] = *(const bf16x8*)&xA[(rbase + m16) * TLD + ks * 32 + g * 8];

    f32x4 acc[6];
    #pragma unroll
    for (int nt = 0; nt < 6; ++nt) {
        f32x4 c = {0.f, 0.f, 0.f, 0.f};
        #pragma unroll
        for (int ks = 0; ks < 3; ++ks) {
            bf16x8 bfrag = *(const bf16x8*)&WT[(nt * 16 + m16) * TLD + ks * 32 + g * 8];
            c = __builtin_amdgcn_mfma_f32_16x16x32_bf16(afrag[ks], bfrag, c, 0, 0, 0);
        }
        acc[nt] = c;
    }

    // epilogue: C layout col = lane&15, row = g*4 + reg  [verified m89/m91]
    float s[4];
    #pragma unroll
    for (int r = 0; r < 4; ++r) {
        int row = r0 + rbase + g * 4 + r;
        int d = (row < nrows) ? deg_out[row] : 1;
        s[r] = (d > 0) ? rsqrtf((float)d) : 0.f;
    }
    #pragma unroll
    for (int nt = 0; nt < 6; ++nt) {
        #pragma unroll
        for (int r = 0; r < 4; ++r) {
            int row = r0 + rbase + g * 4 + r;
            if (row < nrows)
                h[(size_t)row * 96 + nt * 16 + m16] = b1(acc[nt][r] * s[r]);
        }
    }
}

// ---- pass 6: aggregate  out[n] = inv_sqrt_in[n] * sum h[src_e] + b ----
// 16 lanes/node (4 quarters x 4 col-lanes), csr segment staged in LDS.
__device__ __forceinline__ void upadd(float* a, uint4 q) {
    a[0] += __uint_as_float(q.x << 16);
    a[1] += __uint_as_float(q.x & 0xffff0000u);
    a[2] += __uint_as_float(q.y << 16);
    a[3] += __uint_as_float(q.y & 0xffff0000u);
    a[4] += __uint_as_float(q.z << 16);
    a[5] += __uint_as_float(q.z & 0xffff0000u);
    a[6] += __uint_as_float(q.w << 16);
    a[7] += __uint_as_float(q.w & 0xffff0000u);
}

#define AGG_NODES 16
#define IDX_CAP 2048
__global__ __launch_bounds__(256) void agg_kernel(
    const unsigned short* __restrict__ h, const int* __restrict__ csr_src,
    const int* __restrict__ offs, const float* __restrict__ b,
    float* __restrict__ out) {
    __shared__ int sh_idx[IDX_CAP];
    __shared__ int sh_off[AGG_NODES + 1];
    int tid = threadIdx.x;
    int n0 = blockIdx.x * AGG_NODES;                  // N_NODES % 16 == 0 -> no tail
    if (tid <= AGG_NODES) sh_off[tid] = offs[n0 + tid];
    __syncthreads();
    int s0 = sh_off[0];
    int len = sh_off[AGG_NODES] - s0;
    bool lds_ok = (len <= IDX_CAP);
    if (lds_ok) {
        for (int i = tid; i < len; i += 256) sh_idx[i] = csr_src[s0 + i];
    }
    __syncthreads();

    int node = tid >> 4;
    int lane16 = tid & 15;
    int j = lane16 & 3;          // uint4 slots j, j+4, j+8 of the 12-uint4 row
    int q = lane16 >> 2;         // edge quarter 0..3
    int start = sh_off[node], end = sh_off[node + 1];
    float acc[24];
    #pragma unroll
    for (int i = 0; i < 24; ++i) acc[i] = 0.f;
    const uint4* hb = (const uint4*)h;               // row = 12 uint4 (192 B)

    int e = start + q;
    for (; e + 4 < end; e += 8) {
        int i0 = lds_ok ? sh_idx[e - s0] : csr_src[e];
        int i1 = lds_ok ? sh_idx[e + 4 - s0] : csr_src[e + 4];
        size_t b0 = (size_t)i0 * 12 + j;
        size_t b1 = (size_t)i1 * 12 + j;
        uint4 q0 = hb[b0], q1 = hb[b0 + 4], q2 = hb[b0 + 8];
        uint4 p0 = hb[b1], p1 = hb[b1 + 4], p2 = hb[b1 + 8];
        upadd(acc + 0, q0); upadd(acc + 8, q1); upadd(acc + 16, q2);
        upadd(acc + 0, p0); upadd(acc + 8, p1); upadd(acc + 16, p2);
    }
    if (e < end) {
        int i0 = lds_ok ? sh_idx[e - s0] : csr_src[e];
        size_t b0 = (size_t)i0 * 12 + j;
        uint4 q0 = hb[b0], q1 = hb[b0 + 4], q2 = hb[b0 + 8];
        upadd(acc + 0, q0); upadd(acc + 8, q1); upadd(acc + 16, q2);
    }
    // combine quarters (lanes node*16 .. node*16+15; xor 4,8 stay in-group)
    #pragma unroll
    for (int i = 0; i < 24; ++i) {
        acc[i] += __shfl_xor(acc[i], 4, 64);
        acc[i] += __shfl_xor(acc[i], 8, 64);
    }
    if (q != 0) return;
    float inv = (end > start) ? rsqrtf((float)(end - start)) : 0.f;
    int n = n0 + node;
    #pragma unroll
    for (int g = 0; g < 3; ++g) {
        int slot = j + 4 * g;             // cols 8*slot .. 8*slot+7
        float4 bb0 = *(const float4*)(b + 8 * slot);
        float4 bb1 = *(const float4*)(b + 8 * slot + 4);
        float4 r0, r1;
        r0.x = acc[g * 8 + 0] * inv + bb0.x;
        r0.y = acc[g * 8 + 1] * inv + bb0.y;
        r0.z = acc[g * 8 + 2] * inv + bb0.z;
        r0.w = acc[g * 8 + 3] * inv + bb0.w;
        r1.x = acc[g * 8 + 4] * inv + bb1.x;
        r1.y = acc[g * 8 + 5] * inv + bb1.y;
        r1.z = acc[g * 8 + 6] * inv + bb1.z;
        r1.w = acc[g * 8 + 7] * inv + bb1.w;
        float4* o = (float4*)(out + (size_t)n * DFEAT + 8 * slot);
        o[0] = r0; o[1] = r1;
    }
}

extern "C" void kernel_launch(void* const* d_in, const int* in_sizes, int n_in,
                              void* d_out, int out_size, void* d_ws, size_t ws_size,
                              hipStream_t stream) {
    const float* x  = (const float*)d_in[0];
    const float* W  = (const float*)d_in[1];
    const float* b  = (const float*)d_in[2];
    const int*   src = (const int*)d_in[3];
    const int*   dst = (const int*)d_in[4];
    float* out = (float*)d_out;

    // workspace layout (no aliasing; ws is ~268 MB)
    int* deg_out = (int*)d_ws;                   // 50000
    int* deg_in  = deg_out + N_NODES;            // 50000
    int* offs    = deg_in + N_NODES;             // 50001
    int* csr_src = offs + N_NODES + 1;           // 800000
    int* bsum    = csr_src + N_EDGES;            // 196
    size_t tbl_off = (((size_t)(3 * N_NODES + 1 + N_EDGES + 256)) * 4 + 255) & ~(size_t)255;
    int* pout = (int*)((char*)d_ws + tbl_off);               // 4*40*16384 ints (10.5 MB)
    int* pin  = pout + ((size_t)NRANGE * NCHUNK << RBITS);   // 10.5 MB
    size_t h_off = tbl_off + 2 * (((size_t)NRANGE * NCHUNK << RBITS) * 4);
    h_off = (h_off + 255) & ~(size_t)255;
    unsigned short* h = (unsigned short*)((char*)d_ws + h_off);  // 50000*96 bf16 (9.6 MB)

    deg_hist_kernel<<<NRANGE * NCHUNK, 256, 0, stream>>>(src, dst, pout, pin);

    int nb = (N_NODES + 255) / 256;  // 196
    deg_reduce_kernel<<<nb, 256, 0, stream>>>(pout, pin, deg_out, deg_in, bsum);
    scan_final_kernel<<<nb, 256, 0, stream>>>(deg_in, bsum, offs, nb);

    fill_kernel<<<FILL_BLOCKS, 256, 0, stream>>>(src, dst, offs, pin, csr_src);

    gemm_kernel<<<(N_NODES + GEMM_ROWS - 1) / GEMM_ROWS, 256, 0, stream>>>(
        x, W, deg_out, h, N_NODES);

    agg_kernel<<<N_NODES / AGG_NODES, 256, 0, stream>>>(h, csr_src, offs, b, out);
}